// Round 1
// baseline (527.956 us; speedup 1.0000x reference)
//
#include <hip/hip_runtime.h>
#include <hip/hip_bf16.h>
#include <math.h>

// Problem constants
#define B_   4
#define S_   1024
#define CIN  1024
#define H_   16
#define CH   64
#define HC   1024   // H_*CH

typedef __bf16 bf16;
typedef __bf16 bf16x8 __attribute__((ext_vector_type(8)));
typedef __bf16 bf16x4 __attribute__((ext_vector_type(4)));
typedef float  f32x4  __attribute__((ext_vector_type(4)));

// ---------- async global->LDS (16B per lane, wave-uniform LDS base) ----------
__device__ __forceinline__ void gld16(const bf16* g, bf16* l) {
  __builtin_amdgcn_global_load_lds(
      (const __attribute__((address_space(1))) unsigned int*)g,
      (__attribute__((address_space(3))) unsigned int*)l,
      16, 0, 0);
}

// ---------- cast x (f32) -> bf16 ----------
__global__ __launch_bounds__(256) void cast_x_kernel(const float* __restrict__ x,
                                                     bf16* __restrict__ xb) {
  int i = (blockIdx.x * 256 + threadIdx.x) * 4;
  f32x4 v = *(const f32x4*)(x + i);
  bf16x4 o;
  o[0] = (bf16)v[0]; o[1] = (bf16)v[1]; o[2] = (bf16)v[2]; o[3] = (bf16)v[3];
  *(bf16x4*)(xb + i) = o;
}

// ---------- transpose + cast the four 1024x1024 weights -> bf16 (N x K) ----------
__global__ __launch_bounds__(256) void transW_kernel(
    const float* __restrict__ Wq, const float* __restrict__ Wk,
    const float* __restrict__ Wv, const float* __restrict__ Wo,
    bf16* __restrict__ Wqt, bf16* __restrict__ Wkt,
    bf16* __restrict__ Wvt, bf16* __restrict__ Wot) {
  const float* W; bf16* Wt;
  switch (blockIdx.z) {
    case 0: W = Wq; Wt = Wqt; break;
    case 1: W = Wk; Wt = Wkt; break;
    case 2: W = Wv; Wt = Wvt; break;
    default: W = Wo; Wt = Wot; break;
  }
  __shared__ float tile[64][65];
  const int r0 = blockIdx.y * 64, c0 = blockIdx.x * 64;
  const int tx = threadIdx.x & 63, ty = threadIdx.x >> 6;  // 4 rows per pass
#pragma unroll
  for (int j = 0; j < 64; j += 4)
    tile[ty + j][tx] = W[(size_t)(r0 + ty + j) * 1024 + c0 + tx];
  __syncthreads();
#pragma unroll
  for (int j = 0; j < 64; j += 4)
    Wt[(size_t)(c0 + ty + j) * 1024 + r0 + tx] = (bf16)tile[tx][ty + j];
}

// ---------- bf16 GEMM: C(M=4096,N=1024) = A(M,K=1024) @ Bt(N,K)^T ----------
// MODE 0: write bf16 to (B,H,S,c) layout, scaled.   MODE 1: write f32 + bias.
template <int MODE>
__global__ __launch_bounds__(256) void gemm_kernel(
    const bf16* __restrict__ A, const bf16* __restrict__ Bt,
    bf16* __restrict__ outb, float* __restrict__ outf,
    const float* __restrict__ bo, float scale) {
  __shared__ bf16 Asm[128 * 32];
  __shared__ bf16 Bsm[128 * 32];
  const int tid = threadIdx.x;
  const int lane = tid & 63, wave = tid >> 6;
  const int m0 = blockIdx.y * 128, n0 = blockIdx.x * 128;
  const int wr = wave >> 1, wc = wave & 1;   // 2x2 wave grid, 64x64 per wave
  const int K = 1024;

  f32x4 acc[4][4] = {};

  const int srow = tid >> 2;           // 0..63
  const int scol = (tid & 3) * 8;      // 0,8,16,24 (bf16 elements)
  const size_t abase = (size_t)(m0 + srow) * K + scol;
  const size_t bbase = (size_t)(n0 + srow) * K + scol;
  bf16* lA = Asm + wave * 512;         // wave-uniform: wave*1024 bytes
  bf16* lB = Bsm + wave * 512;

  for (int kt = 0; kt < K; kt += 32) {
    gld16(A + abase + kt, lA);
    gld16(A + abase + (size_t)64 * K + kt, lA + 2048);
    gld16(Bt + bbase + kt, lB);
    gld16(Bt + bbase + (size_t)64 * K + kt, lB + 2048);
    __syncthreads();
    bf16x8 af[4], bfr[4];
#pragma unroll
    for (int m = 0; m < 4; m++)
      af[m] = *(const bf16x8*)(Asm + (wr * 64 + m * 16 + (lane & 15)) * 32 + (lane >> 4) * 8);
#pragma unroll
    for (int n = 0; n < 4; n++)
      bfr[n] = *(const bf16x8*)(Bsm + (wc * 64 + n * 16 + (lane & 15)) * 32 + (lane >> 4) * 8);
#pragma unroll
    for (int m = 0; m < 4; m++)
#pragma unroll
      for (int n = 0; n < 4; n++)
        acc[m][n] = __builtin_amdgcn_mfma_f32_16x16x32_bf16(af[m], bfr[n], acc[m][n], 0, 0, 0);
    __syncthreads();
  }

#pragma unroll
  for (int m = 0; m < 4; m++) {
#pragma unroll
    for (int n = 0; n < 4; n++) {
      const int col = n0 + wc * 64 + n * 16 + (lane & 15);
      const int grow = m0 + wr * 64 + m * 16 + (lane >> 4) * 4;
      if (MODE == 0) {
        const int h = col >> 6, c = col & 63;
#pragma unroll
        for (int r = 0; r < 4; r++) {
          const int gr = grow + r;
          const int b = gr >> 10, s = gr & 1023;
          outb[(((size_t)b * H_ + h) * S_ + s) * CH + c] = (bf16)(acc[m][n][r] * scale);
        }
      } else {
        const float bv = bo[col];
#pragma unroll
        for (int r = 0; r < 4; r++)
          outf[(size_t)(grow + r) * 1024 + col] = acc[m][n][r] + bv;
      }
    }
  }
}

// ---------- V (B,H,S,c) -> Vt (B,H,c,S) ----------
__global__ __launch_bounds__(256) void vtrans_kernel(const bf16* __restrict__ V,
                                                     bf16* __restrict__ Vt) {
  const int bh = blockIdx.y;
  const int s0 = blockIdx.x * 64;
  __shared__ bf16 tile[64][72];
  const int tid = threadIdx.x;
  const int row = tid >> 2;            // 0..63
  const int col = (tid & 3) * 16;      // 0,16,32,48
  const bf16* src = V + (size_t)bh * S_ * CH;
  bf16* dst = Vt + (size_t)bh * CH * S_;
  *(bf16x8*)&tile[row][col]     = *(const bf16x8*)(src + (size_t)(s0 + row) * CH + col);
  *(bf16x8*)&tile[row][col + 8] = *(const bf16x8*)(src + (size_t)(s0 + row) * CH + col + 8);
  __syncthreads();
  bf16x8 o0, o1;
#pragma unroll
  for (int j = 0; j < 8; j++) { o0[j] = tile[col + j][row]; o1[j] = tile[col + 8 + j][row]; }
  *(bf16x8*)(dst + (size_t)row * S_ + s0 + col)     = o0;
  *(bf16x8*)(dst + (size_t)row * S_ + s0 + col + 8) = o1;
}

// ---------- flash attention: Q(B,H,S,c) K(B,H,S,c) Vt(B,H,c,S) + bias + mask -> O(B,S,H*c) bf16 ----------
__global__ __launch_bounds__(256) void attn_kernel(
    const bf16* __restrict__ Q, const bf16* __restrict__ Ka,
    const bf16* __restrict__ Vt, const float* __restrict__ bias,
    const int* __restrict__ mask, bf16* __restrict__ O) {
  const int bh = blockIdx.y, b = bh >> 4, h = bh & 15;
  const int q0 = blockIdx.x * 64;
  const int tid = threadIdx.x, wave = tid >> 6, lane = tid & 63;
  const int qr = lane & 15, kg = lane >> 4;
  __shared__ bf16 Ksm[64][72];
  __shared__ bf16 Vsm[64][72];
  __shared__ bf16 Psm[4][16][72];

  // Q fragments for this wave's 16 q-rows (Q pre-scaled by 1/8)
  const bf16* Qp = Q + ((size_t)bh * S_ + q0 + wave * 16 + qr) * CH;
  bf16x8 qf[2];
  qf[0] = *(const bf16x8*)(Qp + kg * 8);
  qf[1] = *(const bf16x8*)(Qp + 32 + kg * 8);

  f32x4 oacc[4] = {};
  float mrow[4] = {-1e30f, -1e30f, -1e30f, -1e30f};
  float lrow[4] = {0.f, 0.f, 0.f, 0.f};

  const float* biasp = bias + ((size_t)bh * S_ + q0 + wave * 16 + kg * 4) * S_;
  const int* maskp = mask + b * S_;
  const bf16* Kp = Ka + (size_t)bh * S_ * CH;
  const bf16* Vp = Vt + (size_t)bh * CH * S_;

  const int srow = tid >> 2, scol = (tid & 3) * 16;

  for (int k0 = 0; k0 < S_; k0 += 64) {
    // cooperative stage of K tile (64 k x 64 c) and Vt tile (64 c x 64 k)
    *(bf16x8*)&Ksm[srow][scol]     = *(const bf16x8*)(Kp + (size_t)(k0 + srow) * CH + scol);
    *(bf16x8*)&Ksm[srow][scol + 8] = *(const bf16x8*)(Kp + (size_t)(k0 + srow) * CH + scol + 8);
    *(bf16x8*)&Vsm[srow][scol]     = *(const bf16x8*)(Vp + (size_t)srow * S_ + k0 + scol);
    *(bf16x8*)&Vsm[srow][scol + 8] = *(const bf16x8*)(Vp + (size_t)srow * S_ + k0 + scol + 8);
    __syncthreads();

    // S = Q @ K^T  (4 col-frags of 16, K-dim = c = 64 -> 2 MFMA k-steps)
    f32x4 sf[4] = {};
#pragma unroll
    for (int n = 0; n < 4; n++) {
#pragma unroll
      for (int j = 0; j < 2; j++) {
        bf16x8 kf = *(const bf16x8*)&Ksm[n * 16 + qr][j * 32 + kg * 8];
        sf[n] = __builtin_amdgcn_mfma_f32_16x16x32_bf16(qf[j], kf, sf[n], 0, 0, 0);
      }
    }
    // + bias + mask offset
#pragma unroll
    for (int n = 0; n < 4; n++) {
      const int col = k0 + n * 16 + qr;
      const float moff = (maskp[col] == 0) ? -1e8f : 0.0f;
#pragma unroll
      for (int r = 0; r < 4; r++)
        sf[n][r] += biasp[(size_t)r * S_ + col] + moff;
    }
    // online softmax (row = kg*4 + r; cols live in 16 lanes of the group)
#pragma unroll
    for (int r = 0; r < 4; r++) {
      float tm = fmaxf(fmaxf(sf[0][r], sf[1][r]), fmaxf(sf[2][r], sf[3][r]));
      tm = fmaxf(tm, __shfl_xor(tm, 1));
      tm = fmaxf(tm, __shfl_xor(tm, 2));
      tm = fmaxf(tm, __shfl_xor(tm, 4));
      tm = fmaxf(tm, __shfl_xor(tm, 8));
      const float nm = fmaxf(mrow[r], tm);
      const float al = __expf(mrow[r] - nm);
      mrow[r] = nm;
      float rs = 0.f;
#pragma unroll
      for (int n = 0; n < 4; n++) {
        const float p = __expf(sf[n][r] - nm);
        sf[n][r] = p;
        rs += p;
      }
      rs += __shfl_xor(rs, 1);
      rs += __shfl_xor(rs, 2);
      rs += __shfl_xor(rs, 4);
      rs += __shfl_xor(rs, 8);
      lrow[r] = lrow[r] * al + rs;
#pragma unroll
      for (int n = 0; n < 4; n++) oacc[n][r] *= al;
    }
    // P (C/D layout) -> per-wave LDS -> A-fragment layout
#pragma unroll
    for (int n = 0; n < 4; n++)
#pragma unroll
      for (int r = 0; r < 4; r++)
        Psm[wave][kg * 4 + r][n * 16 + qr] = (bf16)sf[n][r];
    __asm__ volatile("s_waitcnt lgkmcnt(0)" ::: "memory");
    // O += P @ V
#pragma unroll
    for (int n = 0; n < 4; n++) {
#pragma unroll
      for (int j = 0; j < 2; j++) {
        bf16x8 pf = *(const bf16x8*)&Psm[wave][qr][j * 32 + kg * 8];
        bf16x8 vf = *(const bf16x8*)&Vsm[n * 16 + qr][j * 32 + kg * 8];
        oacc[n] = __builtin_amdgcn_mfma_f32_16x16x32_bf16(pf, vf, oacc[n], 0, 0, 0);
      }
    }
    __syncthreads();
  }
  // normalize + write O in (B,S,H*c) bf16
#pragma unroll
  for (int r = 0; r < 4; r++) {
    const float inv = 1.0f / lrow[r];
    const int s = q0 + wave * 16 + kg * 4 + r;
#pragma unroll
    for (int n = 0; n < 4; n++)
      O[((size_t)b * S_ + s) * HC + h * CH + n * 16 + qr] = (bf16)(oacc[n][r] * inv);
  }
}

extern "C" void kernel_launch(void* const* d_in, const int* in_sizes, int n_in,
                              void* d_out, int out_size, void* d_ws, size_t ws_size,
                              hipStream_t stream) {
  (void)in_sizes; (void)n_in; (void)out_size; (void)ws_size;
  const float* x    = (const float*)d_in[0];
  const float* bias = (const float*)d_in[1];
  const int*   mask = (const int*)d_in[2];
  const float* Wq   = (const float*)d_in[3];
  const float* Wk   = (const float*)d_in[4];
  const float* Wv   = (const float*)d_in[5];
  const float* Wo   = (const float*)d_in[6];
  const float* bo   = (const float*)d_in[7];
  float* out = (float*)d_out;

  char* ws = (char*)d_ws;
  bf16* xb  = (bf16*)(ws);                     // 8 MB
  bf16* Wqt = (bf16*)(ws + (8u  << 20));       // 2 MB each
  bf16* Wkt = (bf16*)(ws + (10u << 20));
  bf16* Wvt = (bf16*)(ws + (12u << 20));
  bf16* Wot = (bf16*)(ws + (14u << 20));
  bf16* Qa  = (bf16*)(ws + (16u << 20));       // 8 MB (B,H,S,c)
  bf16* Kaa = (bf16*)(ws + (24u << 20));       // 8 MB (B,H,S,c)
  bf16* Va  = (bf16*)(ws + (32u << 20));       // 8 MB (B,H,S,c)
  bf16* Vtr = (bf16*)(ws + (40u << 20));       // 8 MB (B,H,c,S)
  bf16* Oa  = (bf16*)(ws + (48u << 20));       // 8 MB (B,S,H*c)

  cast_x_kernel<<<4096, 256, 0, stream>>>(x, xb);
  transW_kernel<<<dim3(16, 16, 4), 256, 0, stream>>>(Wq, Wk, Wv, Wo, Wqt, Wkt, Wvt, Wot);
  gemm_kernel<0><<<dim3(8, 32), 256, 0, stream>>>(xb, Wqt, Qa, nullptr, nullptr, 0.125f);
  gemm_kernel<0><<<dim3(8, 32), 256, 0, stream>>>(xb, Wkt, Kaa, nullptr, nullptr, 1.0f);
  gemm_kernel<0><<<dim3(8, 32), 256, 0, stream>>>(xb, Wvt, Va, nullptr, nullptr, 1.0f);
  vtrans_kernel<<<dim3(16, 64), 256, 0, stream>>>(Va, Vtr);
  attn_kernel<<<dim3(16, 64), 256, 0, stream>>>(Qa, Kaa, Vtr, bias, mask, Oa);
  gemm_kernel<1><<<dim3(8, 32), 256, 0, stream>>>(Oa, Wot, nullptr, out, bo, 1.0f);
}

// Round 2
// 489.705 us; speedup vs baseline: 1.0781x; 1.0781x over previous
//
#include <hip/hip_runtime.h>
#include <hip/hip_bf16.h>
#include <math.h>

// Problem constants
#define B_   4
#define S_   1024
#define CIN  1024
#define H_   16
#define CH   64
#define HC   1024   // H_*CH

typedef __bf16 bf16;
typedef __bf16 bf16x8 __attribute__((ext_vector_type(8)));
typedef __bf16 bf16x4 __attribute__((ext_vector_type(4)));
typedef float  f32x4  __attribute__((ext_vector_type(4)));

// ---------- async global->LDS (16B per lane, wave-uniform LDS base) ----------
__device__ __forceinline__ void gld16(const bf16* g, bf16* l) {
  __builtin_amdgcn_global_load_lds(
      (const __attribute__((address_space(1))) unsigned int*)g,
      (__attribute__((address_space(3))) unsigned int*)l,
      16, 0, 0);
}

// ---------- cast x (f32) -> bf16 ----------
__global__ __launch_bounds__(256) void cast_x_kernel(const float* __restrict__ x,
                                                     bf16* __restrict__ xb) {
  int i = (blockIdx.x * 256 + threadIdx.x) * 4;
  f32x4 v = *(const f32x4*)(x + i);
  bf16x4 o;
  o[0] = (bf16)v[0]; o[1] = (bf16)v[1]; o[2] = (bf16)v[2]; o[3] = (bf16)v[3];
  *(bf16x4*)(xb + i) = o;
}

// ---------- transpose + cast the four 1024x1024 weights -> bf16 (N x K) ----------
// z=0..2 -> rows z*1024 of Wqkvt (3072x1024); z=3 -> Wot (1024x1024)
__global__ __launch_bounds__(256) void transW_kernel(
    const float* __restrict__ Wq, const float* __restrict__ Wk,
    const float* __restrict__ Wv, const float* __restrict__ Wo,
    bf16* __restrict__ Wqkvt, bf16* __restrict__ Wot) {
  const float* W; bf16* Wt;
  switch (blockIdx.z) {
    case 0: W = Wq; Wt = Wqkvt; break;
    case 1: W = Wk; Wt = Wqkvt + (size_t)1024 * 1024; break;
    case 2: W = Wv; Wt = Wqkvt + (size_t)2048 * 1024; break;
    default: W = Wo; Wt = Wot; break;
  }
  __shared__ float tile[64][65];
  const int r0 = blockIdx.y * 64, c0 = blockIdx.x * 64;
  const int tx = threadIdx.x & 63, ty = threadIdx.x >> 6;  // 4 rows per pass
#pragma unroll
  for (int j = 0; j < 64; j += 4)
    tile[ty + j][tx] = W[(size_t)(r0 + ty + j) * 1024 + c0 + tx];
  __syncthreads();
#pragma unroll
  for (int j = 0; j < 64; j += 4)
    Wt[(size_t)(c0 + ty + j) * 1024 + r0 + tx] = (bf16)tile[tx][ty + j];
}

// ---------- bf16 GEMM: C(M=4096,N) = A(M,K=1024) @ Bt(N,K)^T ----------
// MODE 0: fused QKV (N=3072): Q bf16 scaled -> (B,H,S,c); K bf16 -> (B,H,S,c);
//         V bf16 -> transposed (B,H,c,S).
// MODE 1: out-proj (N=1024): f32 + bias -> (B*S, 1024)
template <int MODE>
__global__ __launch_bounds__(256) void gemm_kernel(
    const bf16* __restrict__ A, const bf16* __restrict__ Bt,
    bf16* __restrict__ Qa, bf16* __restrict__ Ka, bf16* __restrict__ Vt,
    float* __restrict__ outf, const float* __restrict__ bo) {
  __shared__ bf16 Asm[128 * 32];
  __shared__ bf16 Bsm[128 * 32];
  const int tid = threadIdx.x;
  const int lane = tid & 63, wave = tid >> 6;
  const int m0 = blockIdx.y * 128, n0 = blockIdx.x * 128;
  const int wr = wave >> 1, wc = wave & 1;   // 2x2 wave grid, 64x64 per wave
  const int K = 1024;

  f32x4 acc[4][4] = {};

  const int srow = tid >> 2;           // 0..63
  const int scol = (tid & 3) * 8;      // 0,8,16,24 (bf16 elements)
  const size_t abase = (size_t)(m0 + srow) * K + scol;
  const size_t bbase = (size_t)(n0 + srow) * K + scol;
  bf16* lA = Asm + wave * 512;         // wave-uniform: wave*1024 bytes
  bf16* lB = Bsm + wave * 512;

  for (int kt = 0; kt < K; kt += 32) {
    gld16(A + abase + kt, lA);
    gld16(A + abase + (size_t)64 * K + kt, lA + 2048);
    gld16(Bt + bbase + kt, lB);
    gld16(Bt + bbase + (size_t)64 * K + kt, lB + 2048);
    __syncthreads();
    bf16x8 af[4], bfr[4];
#pragma unroll
    for (int m = 0; m < 4; m++)
      af[m] = *(const bf16x8*)(Asm + (wr * 64 + m * 16 + (lane & 15)) * 32 + (lane >> 4) * 8);
#pragma unroll
    for (int n = 0; n < 4; n++)
      bfr[n] = *(const bf16x8*)(Bsm + (wc * 64 + n * 16 + (lane & 15)) * 32 + (lane >> 4) * 8);
    __builtin_amdgcn_s_setprio(1);
#pragma unroll
    for (int m = 0; m < 4; m++)
#pragma unroll
      for (int n = 0; n < 4; n++)
        acc[m][n] = __builtin_amdgcn_mfma_f32_16x16x32_bf16(af[m], bfr[n], acc[m][n], 0, 0, 0);
    __builtin_amdgcn_s_setprio(0);
    __syncthreads();
  }

#pragma unroll
  for (int m = 0; m < 4; m++) {
#pragma unroll
    for (int n = 0; n < 4; n++) {
      const int col = n0 + wc * 64 + n * 16 + (lane & 15);
      const int grow = m0 + wr * 64 + m * 16 + (lane >> 4) * 4;
      if (MODE == 0) {
        const int which = col >> 10;          // wave-uniform (16-col frag within a 1024 block)
        const int hcol = col & 1023, hh = hcol >> 6, cc = hcol & 63;
        const int bb = grow >> 10, s0v = grow & 1023;
        if (which == 0) {
          const size_t base = (((size_t)bb * H_ + hh) * S_ + s0v) * CH + cc;
#pragma unroll
          for (int r = 0; r < 4; r++)
            Qa[base + (size_t)r * CH] = (bf16)(acc[m][n][r] * 0.125f);
        } else if (which == 1) {
          const size_t base = (((size_t)bb * H_ + hh) * S_ + s0v) * CH + cc;
#pragma unroll
          for (int r = 0; r < 4; r++)
            Ka[base + (size_t)r * CH] = (bf16)acc[m][n][r];
        } else {
          bf16x4 pv;
#pragma unroll
          for (int r = 0; r < 4; r++) pv[r] = (bf16)acc[m][n][r];
          *(bf16x4*)(Vt + (((size_t)bb * H_ + hh) * CH + cc) * S_ + s0v) = pv;
        }
      } else {
        const float bv = bo[col];
#pragma unroll
        for (int r = 0; r < 4; r++)
          outf[(size_t)(grow + r) * 1024 + col] = acc[m][n][r] + bv;
      }
    }
  }
}

// ---------- flash attention ----------
// Q(B,H,S,c) K(B,H,S,c) Vt(B,H,c,S) + bias(B,H,S,S) + mask(B,S) -> O(B,S,H*c) bf16
__global__ __launch_bounds__(256) void attn_kernel(
    const bf16* __restrict__ Q, const bf16* __restrict__ Ka,
    const bf16* __restrict__ Vt, const float* __restrict__ bias,
    const int* __restrict__ mask, bf16* __restrict__ O) {
  const int bh = blockIdx.y, b = bh >> 4, h = bh & 15;
  const int q0 = blockIdx.x * 64;
  const int tid = threadIdx.x, wave = tid >> 6, lane = tid & 63;
  const int qr = lane & 15, kg = lane >> 4;

  __shared__ bf16 Ksm[64][72];
  __shared__ bf16 Vsm[64][72];
  __shared__ bf16 Psm[4][16][72];
  __shared__ float Bsm[64][68];
  __shared__ float Msm[S_];

  // mask -> additive offsets, staged once (coalesced int4)
  {
    const int4 mv = *(const int4*)(mask + (size_t)b * S_ + tid * 4);
    f32x4 mo;
    mo[0] = (mv.x == 0) ? -1e8f : 0.f;
    mo[1] = (mv.y == 0) ? -1e8f : 0.f;
    mo[2] = (mv.z == 0) ? -1e8f : 0.f;
    mo[3] = (mv.w == 0) ? -1e8f : 0.f;
    *(f32x4*)(Msm + tid * 4) = mo;
  }

  // Q fragments for this wave's 16 q-rows (Q pre-scaled by 1/8)
  const bf16* Qp = Q + ((size_t)bh * S_ + q0 + wave * 16 + qr) * CH;
  bf16x8 qf[2];
  qf[0] = *(const bf16x8*)(Qp + kg * 8);
  qf[1] = *(const bf16x8*)(Qp + 32 + kg * 8);

  f32x4 oacc[4] = {};
  float mrow[4] = {-1e30f, -1e30f, -1e30f, -1e30f};
  float lrow[4] = {0.f, 0.f, 0.f, 0.f};

  const bf16* Kp = Ka + (size_t)bh * S_ * CH;
  const bf16* Vp = Vt + (size_t)bh * CH * S_;
  const float* biasT = bias + ((size_t)bh * S_ + q0) * S_;  // 64 x S tile base

  // staging coords
  const int srow = tid >> 2, scol = (tid & 3) * 16;  // K/V: 64 rows x 32B halves
  const int brow = tid >> 4, bcol = (tid & 15) * 4;  // bias: 16 rows/round x 16B

  // prefetch registers
  bf16x8 kr0, kr1, vr0, vr1;
  f32x4 brg[4];

  // prologue: load tile 0
  {
    const int k0 = 0;
    kr0 = *(const bf16x8*)(Kp + (size_t)(k0 + srow) * CH + scol);
    kr1 = *(const bf16x8*)(Kp + (size_t)(k0 + srow) * CH + scol + 8);
    vr0 = *(const bf16x8*)(Vp + (size_t)srow * S_ + k0 + scol);
    vr1 = *(const bf16x8*)(Vp + (size_t)srow * S_ + k0 + scol + 8);
#pragma unroll
    for (int i = 0; i < 4; i++)
      brg[i] = *(const f32x4*)(biasT + (size_t)(brow + i * 16) * S_ + k0 + bcol);
  }

  for (int t = 0; t < S_ / 64; t++) {
    const int k0 = t * 64;
    __syncthreads();  // all waves done reading LDS of previous tile
    *(bf16x8*)&Ksm[srow][scol] = kr0;
    *(bf16x8*)&Ksm[srow][scol + 8] = kr1;
    *(bf16x8*)&Vsm[srow][scol] = vr0;
    *(bf16x8*)&Vsm[srow][scol + 8] = vr1;
#pragma unroll
    for (int i = 0; i < 4; i++)
      *(f32x4*)&Bsm[brow + i * 16][bcol] = brg[i];
    // issue next tile's loads (stay in flight across the barrier)
    if (t + 1 < S_ / 64) {
      const int kn = k0 + 64;
      kr0 = *(const bf16x8*)(Kp + (size_t)(kn + srow) * CH + scol);
      kr1 = *(const bf16x8*)(Kp + (size_t)(kn + srow) * CH + scol + 8);
      vr0 = *(const bf16x8*)(Vp + (size_t)srow * S_ + kn + scol);
      vr1 = *(const bf16x8*)(Vp + (size_t)srow * S_ + kn + scol + 8);
#pragma unroll
      for (int i = 0; i < 4; i++)
        brg[i] = *(const f32x4*)(biasT + (size_t)(brow + i * 16) * S_ + kn + bcol);
    }
    __syncthreads();  // K/V/bias tiles visible

    // S = Q @ K^T  (4 col-frags of 16, K-dim = c = 64 -> 2 MFMA k-steps)
    f32x4 sf[4] = {};
    __builtin_amdgcn_s_setprio(1);
#pragma unroll
    for (int n = 0; n < 4; n++) {
#pragma unroll
      for (int j = 0; j < 2; j++) {
        bf16x8 kf = *(const bf16x8*)&Ksm[n * 16 + qr][j * 32 + kg * 8];
        sf[n] = __builtin_amdgcn_mfma_f32_16x16x32_bf16(qf[j], kf, sf[n], 0, 0, 0);
      }
    }
    __builtin_amdgcn_s_setprio(0);
    // + bias + mask offset (both from LDS now)
#pragma unroll
    for (int n = 0; n < 4; n++) {
      const float moff = Msm[k0 + n * 16 + qr];
#pragma unroll
      for (int r = 0; r < 4; r++)
        sf[n][r] += Bsm[wave * 16 + kg * 4 + r][n * 16 + qr] + moff;
    }
    // online softmax (row = kg*4 + r; cols live in the 16 lanes of the group)
#pragma unroll
    for (int r = 0; r < 4; r++) {
      float tm = fmaxf(fmaxf(sf[0][r], sf[1][r]), fmaxf(sf[2][r], sf[3][r]));
      tm = fmaxf(tm, __shfl_xor(tm, 1));
      tm = fmaxf(tm, __shfl_xor(tm, 2));
      tm = fmaxf(tm, __shfl_xor(tm, 4));
      tm = fmaxf(tm, __shfl_xor(tm, 8));
      const float nm = fmaxf(mrow[r], tm);
      const float al = __expf(mrow[r] - nm);
      mrow[r] = nm;
      float rs = 0.f;
#pragma unroll
      for (int n = 0; n < 4; n++) {
        const float p = __expf(sf[n][r] - nm);
        sf[n][r] = p;
        rs += p;
      }
      rs += __shfl_xor(rs, 1);
      rs += __shfl_xor(rs, 2);
      rs += __shfl_xor(rs, 4);
      rs += __shfl_xor(rs, 8);
      lrow[r] = lrow[r] * al + rs;
#pragma unroll
      for (int n = 0; n < 4; n++) oacc[n][r] *= al;
    }
    // P (C/D layout) -> per-wave LDS -> A-fragment layout
#pragma unroll
    for (int n = 0; n < 4; n++)
#pragma unroll
      for (int r = 0; r < 4; r++)
        Psm[wave][kg * 4 + r][n * 16 + qr] = (bf16)sf[n][r];
    __asm__ volatile("s_waitcnt lgkmcnt(0)" ::: "memory");
    // O += P @ V
    __builtin_amdgcn_s_setprio(1);
#pragma unroll
    for (int n = 0; n < 4; n++) {
#pragma unroll
      for (int j = 0; j < 2; j++) {
        bf16x8 pf = *(const bf16x8*)&Psm[wave][qr][j * 32 + kg * 8];
        bf16x8 vf = *(const bf16x8*)&Vsm[n * 16 + qr][j * 32 + kg * 8];
        oacc[n] = __builtin_amdgcn_mfma_f32_16x16x32_bf16(pf, vf, oacc[n], 0, 0, 0);
      }
    }
    __builtin_amdgcn_s_setprio(0);
  }
  // normalize + write O in (B,S,H*c) bf16
#pragma unroll
  for (int r = 0; r < 4; r++) {
    const float inv = 1.0f / lrow[r];
    const int s = q0 + wave * 16 + kg * 4 + r;
#pragma unroll
    for (int n = 0; n < 4; n++)
      O[((size_t)b * S_ + s) * HC + h * CH + n * 16 + qr] = (bf16)(oacc[n][r] * inv);
  }
}

extern "C" void kernel_launch(void* const* d_in, const int* in_sizes, int n_in,
                              void* d_out, int out_size, void* d_ws, size_t ws_size,
                              hipStream_t stream) {
  (void)in_sizes; (void)n_in; (void)out_size; (void)ws_size;
  const float* x    = (const float*)d_in[0];
  const float* bias = (const float*)d_in[1];
  const int*   mask = (const int*)d_in[2];
  const float* Wq   = (const float*)d_in[3];
  const float* Wk   = (const float*)d_in[4];
  const float* Wv   = (const float*)d_in[5];
  const float* Wo   = (const float*)d_in[6];
  const float* bo   = (const float*)d_in[7];
  float* out = (float*)d_out;

  char* ws = (char*)d_ws;
  bf16* xb    = (bf16*)(ws);                    // 8 MB
  bf16* Wqkvt = (bf16*)(ws + (8u  << 20));      // 6 MB (3072 x 1024)
  bf16* Wot   = (bf16*)(ws + (14u << 20));      // 2 MB
  bf16* Qa    = (bf16*)(ws + (16u << 20));      // 8 MB (B,H,S,c)
  bf16* Kaa   = (bf16*)(ws + (24u << 20));      // 8 MB (B,H,S,c)
  bf16* Vtr   = (bf16*)(ws + (32u << 20));      // 8 MB (B,H,c,S)
  bf16* Oa    = (bf16*)(ws + (40u << 20));      // 8 MB (B,S,H*c)

  cast_x_kernel<<<4096, 256, 0, stream>>>(x, xb);
  transW_kernel<<<dim3(16, 16, 4), 256, 0, stream>>>(Wq, Wk, Wv, Wo, Wqkvt, Wot);
  gemm_kernel<0><<<dim3(24, 32), 256, 0, stream>>>(xb, Wqkvt, Qa, Kaa, Vtr, nullptr, nullptr);
  attn_kernel<<<dim3(16, 64), 256, 0, stream>>>(Qa, Kaa, Vtr, bias, mask, Oa);
  gemm_kernel<1><<<dim3(8, 32), 256, 0, stream>>>(Oa, Wot, nullptr, nullptr, nullptr, out, bo);
}